// Round 2
// baseline (639.864 us; speedup 1.0000x reference)
//
#include <hip/hip_runtime.h>
#include <hip/hip_bf16.h>
#include <stdint.h>

#define B_DIM 8192
#define IN_DIM 4096
#define OUT_DIM 4096

typedef __attribute__((ext_vector_type(8))) short s16x8;
typedef __attribute__((ext_vector_type(4))) float f32x4;

__device__ __forceinline__ unsigned short f2bf_rn(float f) {
    unsigned int u = __float_as_uint(f);
    u = (u + 0x7FFFu + ((u >> 16) & 1u)) >> 16;
    return (unsigned short)u;
}

__device__ __forceinline__ void async16(unsigned short* l, const unsigned short* g) {
    __builtin_amdgcn_global_load_lds(
        (const __attribute__((address_space(1))) void*)g,
        (__attribute__((address_space(3))) void*)l, 16, 0, 0);
}

// ---- Kernel 1: per-output-channel weight quantization -----------------------
__global__ __launch_bounds__(256) void quant_w(
    const float* __restrict__ W, const float* __restrict__ b,
    const float* __restrict__ act_sf, unsigned short* __restrict__ wq,
    float* __restrict__ fc_sf_out, float* __restrict__ bb,
    float* __restrict__ gmax)
{
    int o = blockIdx.x;
    int t = threadIdx.x;
    const float4* Wr = (const float4*)(W + (size_t)o * IN_DIM);
    float4 v[4];
    float amax = 0.f;
#pragma unroll
    for (int j = 0; j < 4; ++j) {
        v[j] = Wr[t + j * 256];
        amax = fmaxf(amax, fmaxf(fmaxf(fabsf(v[j].x), fabsf(v[j].y)),
                                 fmaxf(fabsf(v[j].z), fabsf(v[j].w))));
    }
#pragma unroll
    for (int off = 32; off > 0; off >>= 1)
        amax = fmaxf(amax, __shfl_down(amax, off, 64));
    __shared__ float red[4];
    if ((t & 63) == 0) red[t >> 6] = amax;
    __syncthreads();
    float wmax = fmaxf(fmaxf(red[0], red[1]), fmaxf(red[2], red[3]));
    float sf = fmaxf(wmax, 1e-8f) / 127.0f;   // fc_sf

    unsigned short* wr = wq + (size_t)o * IN_DIM;
#pragma unroll
    for (int j = 0; j < 4; ++j) {
        ushort4 q;
        q.x = f2bf_rn(fminf(fmaxf(rintf(v[j].x / sf), -128.f), 127.f));
        q.y = f2bf_rn(fminf(fmaxf(rintf(v[j].y / sf), -128.f), 127.f));
        q.z = f2bf_rn(fminf(fmaxf(rintf(v[j].z / sf), -128.f), 127.f));
        q.w = f2bf_rn(fminf(fmaxf(rintf(v[j].w / sf), -128.f), 127.f));
        ((ushort4*)wr)[t + j * 256] = q;
    }
    if (t == 0) {
        fc_sf_out[o] = sf;
        float bsf = sf * act_sf[0];          // bias_sf
        float bi = rintf(b[o] / bsf);        // b_int
        bb[o] = bi * bsf;                    // folded bias for epilogue
        if (o == 0) gmax[0] = 0.f;           // ws is poisoned each launch
    }
}

// ---- Kernel 2: x -> bf16 (RN), 8 elems/thread ------------------------------
__global__ __launch_bounds__(256) void cvt_x(const float* __restrict__ x,
                                             unsigned short* __restrict__ xq)
{
    size_t i = ((size_t)blockIdx.x * 256 + threadIdx.x) * 8;
#pragma unroll
    for (int j = 0; j < 2; ++j) {
        float4 v = *(const float4*)(x + i + j * 4);
        ushort4 q;
        q.x = f2bf_rn(v.x); q.y = f2bf_rn(v.y);
        q.z = f2bf_rn(v.z); q.w = f2bf_rn(v.w);
        *(ushort4*)(xq + i + j * 4) = q;
    }
}

// ---- Kernel 3: GEMM C = A * B^T, fused scale+bias+ReLU+global-max ----------
// 128x128 tile, BK=32, 4 waves x (4x4) 16x16x32 MFMA.
// LDS layout is XOR-swizzled: chunk c (16B) of row r lives at chunk-slot
// c ^ swz(r), swz(r) = (r&3)^((r>>2)&1)  [period 8]. This makes the
// row-stride-64B ds_read_b128 fragment reads conflict-free (bank-group
// (4*l16 + (q^swz(l16))) mod 8 is a permutation over any 8 lanes) while
// keeping the global_load_lds lane-contiguous write constraint satisfied:
// we permute WHICH global chunk each lane fetches, not where it writes.
__global__ __launch_bounds__(256) void gemm_bt(
    const unsigned short* __restrict__ A, const unsigned short* __restrict__ Bw,
    const float* __restrict__ fc_sf, const float* __restrict__ bb,
    float* __restrict__ C, float* __restrict__ gmax)
{
    __shared__ unsigned short sA[128 * 32];
    __shared__ unsigned short sB[128 * 32];
    __shared__ float redm[4];

    int t = threadIdx.x;
    int bn = blockIdx.x & 31;      // N/128 = 32
    int bm = blockIdx.x >> 5;      // M/128 = 64
    int lane = t & 63;
    int w = t >> 6;
    int quad = lane >> 4;
    int l16 = lane & 15;
    int m0 = bm * 128, n0 = bn * 128;
    int wm = (w & 1) * 64, wn = (w >> 1) * 64;

    // staging: thread t owns LDS slots t and t+256 (16B each).
    // slot s -> row r = s>>2, chunk-slot cs = s&3, global chunk gc = cs^swz(r).
    // rows of slot t and t+256 differ by 64 -> same swz (period 8).
    int r0 = t >> 2;
    int gc = (t & 3) ^ ((r0 & 3) ^ ((r0 >> 2) & 1));
    const unsigned short* gA0 = A + (size_t)(m0 + r0) * IN_DIM + gc * 8;
    const unsigned short* gA1 = A + (size_t)(m0 + 64 + r0) * IN_DIM + gc * 8;
    const unsigned short* gB0 = Bw + (size_t)(n0 + r0) * IN_DIM + gc * 8;
    const unsigned short* gB1 = Bw + (size_t)(n0 + 64 + r0) * IN_DIM + gc * 8;
    unsigned short* lA0 = sA + t * 8;
    unsigned short* lA1 = sA + (t + 256) * 8;
    unsigned short* lB0 = sB + t * 8;
    unsigned short* lB1 = sB + (t + 256) * 8;

    // fragment read: row rr = w?+l16(+16*mi), k-quad q -> chunk-slot q^swz(rr).
    // swz depends only on l16 (wm/wn and 16*mi are multiples of 8).
    int swzl = (l16 & 3) ^ ((l16 >> 2) & 1);
    const unsigned short* pa = sA + (wm + l16) * 32 + ((quad ^ swzl) * 8);
    const unsigned short* pb = sB + (wn + l16) * 32 + ((quad ^ swzl) * 8);

    f32x4 acc[4][4];
#pragma unroll
    for (int mi = 0; mi < 4; ++mi)
#pragma unroll
        for (int ni = 0; ni < 4; ++ni)
            acc[mi][ni] = (f32x4){0.f, 0.f, 0.f, 0.f};

    for (int kk = 0; kk < IN_DIM; kk += 32) {
        __syncthreads();                       // all waves done reading prev tile
        async16(lA0, gA0 + kk);
        async16(lA1, gA1 + kk);
        async16(lB0, gB0 + kk);
        async16(lB1, gB1 + kk);
        asm volatile("s_waitcnt vmcnt(0)" ::: "memory");
        __syncthreads();

        s16x8 af[4], bf[4];
#pragma unroll
        for (int i = 0; i < 4; ++i) af[i] = *(const s16x8*)(pa + i * 16 * 32);
#pragma unroll
        for (int i = 0; i < 4; ++i) bf[i] = *(const s16x8*)(pb + i * 16 * 32);
#pragma unroll
        for (int mi = 0; mi < 4; ++mi)
#pragma unroll
            for (int ni = 0; ni < 4; ++ni)
                acc[mi][ni] = __builtin_amdgcn_mfma_f32_16x16x32_bf16(
                    af[mi], bf[ni], acc[mi][ni], 0, 0, 0);
    }

    // epilogue: C/D layout col = lane&15, row = quad*4 + reg
    float tmax = 0.f;
#pragma unroll
    for (int ni = 0; ni < 4; ++ni) {
        int col = n0 + wn + ni * 16 + l16;
        float s = fc_sf[col];
        float bbv = bb[col];
#pragma unroll
        for (int mi = 0; mi < 4; ++mi) {
            int rowb = m0 + wm + mi * 16 + quad * 4;
#pragma unroll
            for (int r = 0; r < 4; ++r) {
                float vv = acc[mi][ni][r] * s + bbv;
                vv = fmaxf(vv, 0.f);           // ReLU
                tmax = fmaxf(tmax, vv);
                C[(size_t)(rowb + r) * OUT_DIM + col] = vv;
            }
        }
    }
#pragma unroll
    for (int off = 32; off > 0; off >>= 1)
        tmax = fmaxf(tmax, __shfl_down(tmax, off, 64));
    if (lane == 0) redm[w] = tmax;
    __syncthreads();
    if (t == 0) {
        float bmax = fmaxf(fmaxf(redm[0], redm[1]), fmaxf(redm[2], redm[3]));
        atomicMax((int*)gmax, __float_as_int(bmax));   // values >= 0
    }
}

// ---- Kernel 4: per-tensor requant, in place, 8 elems/thread ----------------
__global__ __launch_bounds__(256) void requant(float* __restrict__ C,
    const float* __restrict__ gmax, float* __restrict__ sf_out)
{
    float sf = fmaxf(gmax[0], 1e-8f) / 255.0f;
    size_t i = ((size_t)blockIdx.x * 256 + threadIdx.x) * 8;
#pragma unroll
    for (int j = 0; j < 2; ++j) {
        float4 v = *(const float4*)(C + i + j * 4);
        v.x = fminf(rintf(v.x / sf), 255.f) * sf;
        v.y = fminf(rintf(v.y / sf), 255.f) * sf;
        v.z = fminf(rintf(v.z / sf), 255.f) * sf;
        v.w = fminf(rintf(v.w / sf), 255.f) * sf;
        *(float4*)(C + i + j * 4) = v;
    }
    if (i == 0) sf_out[0] = sf;
}

extern "C" void kernel_launch(void* const* d_in, const int* in_sizes, int n_in,
                              void* d_out, int out_size, void* d_ws, size_t ws_size,
                              hipStream_t stream)
{
    const float* x      = (const float*)d_in[0];
    const float* act_sf = (const float*)d_in[1];
    const float* W      = (const float*)d_in[2];
    const float* b      = (const float*)d_in[3];

    float* out        = (float*)d_out;                       // [8192*4096] x_out
    float* fc_sf_out  = out + (size_t)B_DIM * OUT_DIM;       // [4096]
    float* act_sf_out = fc_sf_out + OUT_DIM;                 // [1]

    char* ws = (char*)d_ws;
    float* bb   = (float*)ws;                                // 4096 floats
    float* gmax = (float*)(ws + 16384);                      // 1 float
    unsigned short* xq = (unsigned short*)(ws + 32768);      // x bf16
    unsigned short* wq = xq + (size_t)B_DIM * IN_DIM;        // w_int bf16

    quant_w<<<OUT_DIM, 256, 0, stream>>>(W, b, act_sf, wq, fc_sf_out, bb, gmax);
    cvt_x<<<(B_DIM * IN_DIM) / 2048, 256, 0, stream>>>(x, xq);
    gemm_bt<<<(B_DIM / 128) * (OUT_DIM / 128), 256, 0, stream>>>(
        xq, wq, fc_sf_out, bb, out, gmax);
    requant<<<(B_DIM * OUT_DIM) / 2048, 256, 0, stream>>>(out, gmax, act_sf_out);
}

// Round 3
// 632.202 us; speedup vs baseline: 1.0121x; 1.0121x over previous
//
#include <hip/hip_runtime.h>
#include <hip/hip_bf16.h>
#include <stdint.h>

#define B_DIM 8192
#define IN_DIM 4096
#define OUT_DIM 4096

typedef __attribute__((ext_vector_type(8))) short s16x8;
typedef __attribute__((ext_vector_type(4))) float f32x4;

__device__ __forceinline__ unsigned short f2bf_rn(float f) {
    unsigned int u = __float_as_uint(f);
    u = (u + 0x7FFFu + ((u >> 16) & 1u)) >> 16;
    return (unsigned short)u;
}

__device__ __forceinline__ void async16(unsigned short* l, const unsigned short* g) {
    __builtin_amdgcn_global_load_lds(
        (const __attribute__((address_space(1))) void*)g,
        (__attribute__((address_space(3))) void*)l, 16, 0, 0);
}

// ---- Kernel 1: fused weight-quant (blocks 0..4095) + x->bf16 (rest) --------
// quant part: one block per output channel o. Computes fc_sf[o], w_int as
// bf16 (exact ints in [-128,127]), bb[o] = round(b/bias_sf)*bias_sf.
// cvt part: 2048 elems per block, fp32 -> bf16 RN.
__global__ __launch_bounds__(256) void prep(
    const float* __restrict__ W, const float* __restrict__ b,
    const float* __restrict__ act_sf, const float* __restrict__ x,
    unsigned short* __restrict__ wq, unsigned short* __restrict__ xq,
    float* __restrict__ fc_sf_out, float* __restrict__ bb,
    float* __restrict__ gmax)
{
    __shared__ float red[4];
    int t = threadIdx.x;
    if (blockIdx.x < OUT_DIM) {
        int o = blockIdx.x;
        const float4* Wr = (const float4*)(W + (size_t)o * IN_DIM);
        float4 v[4];
        float amax = 0.f;
#pragma unroll
        for (int j = 0; j < 4; ++j) {
            v[j] = Wr[t + j * 256];
            amax = fmaxf(amax, fmaxf(fmaxf(fabsf(v[j].x), fabsf(v[j].y)),
                                     fmaxf(fabsf(v[j].z), fabsf(v[j].w))));
        }
#pragma unroll
        for (int off = 32; off > 0; off >>= 1)
            amax = fmaxf(amax, __shfl_down(amax, off, 64));
        if ((t & 63) == 0) red[t >> 6] = amax;
        __syncthreads();
        float wmax = fmaxf(fmaxf(red[0], red[1]), fmaxf(red[2], red[3]));
        float sf = fmaxf(wmax, 1e-8f) / 127.0f;   // fc_sf

        unsigned short* wr = wq + (size_t)o * IN_DIM;
#pragma unroll
        for (int j = 0; j < 4; ++j) {
            ushort4 q;
            q.x = f2bf_rn(fminf(fmaxf(rintf(v[j].x / sf), -128.f), 127.f));
            q.y = f2bf_rn(fminf(fmaxf(rintf(v[j].y / sf), -128.f), 127.f));
            q.z = f2bf_rn(fminf(fmaxf(rintf(v[j].z / sf), -128.f), 127.f));
            q.w = f2bf_rn(fminf(fmaxf(rintf(v[j].w / sf), -128.f), 127.f));
            ((ushort4*)wr)[t + j * 256] = q;
        }
        if (t == 0) {
            fc_sf_out[o] = sf;
            float bsf = sf * act_sf[0];          // bias_sf
            float bi = rintf(b[o] / bsf);        // b_int
            bb[o] = bi * bsf;                    // folded bias
            if (o == 0) gmax[0] = 0.f;           // ws is poisoned each launch
        }
    } else {
        size_t i = ((size_t)(blockIdx.x - OUT_DIM) * 256 + t) * 8;
#pragma unroll
        for (int j = 0; j < 2; ++j) {
            float4 v = *(const float4*)(x + i + j * 4);
            ushort4 q;
            q.x = f2bf_rn(v.x); q.y = f2bf_rn(v.y);
            q.z = f2bf_rn(v.z); q.w = f2bf_rn(v.w);
            *(ushort4*)(xq + i + j * 4) = q;
        }
    }
}

// ---- Kernel 2: GEMM C = A * B^T, fused scale+bias+ReLU+global-max ----------
// 128x128 tile, BK=64 (halved barrier/drain count vs BK=32), 4 waves x (4x4)
// 16x16x32 MFMA, two K-halves per staged tile reusing fragment registers.
// LDS rows are 128B (full bank wrap) so fragment reads REQUIRE the XOR
// swizzle: 16B chunk c of row r lives at chunk-slot c ^ (r&7). Staging
// (global_load_lds, wave-uniform base + lane*16) permutes WHICH global chunk
// each lane fetches; reads then index slot (4h+q) ^ (l16&7), making each
// dword-pass hit 8 distinct bank groups (wave64 2-lane/bank floor = free).
__global__ __launch_bounds__(256) void gemm_bt(
    const unsigned short* __restrict__ A, const unsigned short* __restrict__ Bw,
    const float* __restrict__ fc_sf, const float* __restrict__ bb,
    float* __restrict__ C, float* __restrict__ gmax)
{
    __shared__ unsigned short sA[128 * 64];   // 16 KB
    __shared__ unsigned short sB[128 * 64];   // 16 KB
    __shared__ float redm[4];

    int t = threadIdx.x;
    int bn = blockIdx.x & 31;      // N/128 = 32
    int bm = blockIdx.x >> 5;      // M/128 = 64
    int lane = t & 63;
    int w = t >> 6;
    int quad = lane >> 4;
    int l16 = lane & 15;
    int m0 = bm * 128, n0 = bn * 128;
    int wm = (w & 1) * 64, wn = (w >> 1) * 64;

    // staging: slot s = j*256 + t (j=0..3), row r = s>>3 = j*32 + (t>>3),
    // chunk-slot cs = t&7, global chunk gc = cs ^ (r&7) = (t&7) ^ ((t>>3)&7).
    int r0 = t >> 3;
    int gc = (t & 7) ^ (r0 & 7);
    const unsigned short* gA[4];
    const unsigned short* gB[4];
    unsigned short* lA[4];
    unsigned short* lB[4];
#pragma unroll
    for (int j = 0; j < 4; ++j) {
        gA[j] = A + (size_t)(m0 + j * 32 + r0) * IN_DIM + gc * 8;
        gB[j] = Bw + (size_t)(n0 + j * 32 + r0) * IN_DIM + gc * 8;
        lA[j] = sA + (j * 256 + t) * 8;
        lB[j] = sB + (j * 256 + t) * 8;
    }

    // fragment reads: row = (wm|wn) + l16 + 16*mi (all offsets ≡0 mod 8),
    // half h, k-quad q -> chunk-slot (4h+q) ^ (l16&7).
    int swzl = l16 & 7;
    const unsigned short* pa[2];
    const unsigned short* pb[2];
#pragma unroll
    for (int h = 0; h < 2; ++h) {
        pa[h] = sA + (wm + l16) * 64 + ((4 * h + quad) ^ swzl) * 8;
        pb[h] = sB + (wn + l16) * 64 + ((4 * h + quad) ^ swzl) * 8;
    }

    f32x4 acc[4][4];
#pragma unroll
    for (int mi = 0; mi < 4; ++mi)
#pragma unroll
        for (int ni = 0; ni < 4; ++ni)
            acc[mi][ni] = (f32x4){0.f, 0.f, 0.f, 0.f};

    for (int kk = 0; kk < IN_DIM; kk += 64) {
        __syncthreads();                       // all waves done reading prev tile
#pragma unroll
        for (int j = 0; j < 4; ++j) {
            async16(lA[j], gA[j] + kk);
            async16(lB[j], gB[j] + kk);
        }
        asm volatile("s_waitcnt vmcnt(0)" ::: "memory");
        __syncthreads();

#pragma unroll
        for (int h = 0; h < 2; ++h) {
            s16x8 af[4], bf[4];
#pragma unroll
            for (int i = 0; i < 4; ++i) af[i] = *(const s16x8*)(pa[h] + i * 16 * 64);
#pragma unroll
            for (int i = 0; i < 4; ++i) bf[i] = *(const s16x8*)(pb[h] + i * 16 * 64);
#pragma unroll
            for (int mi = 0; mi < 4; ++mi)
#pragma unroll
                for (int ni = 0; ni < 4; ++ni)
                    acc[mi][ni] = __builtin_amdgcn_mfma_f32_16x16x32_bf16(
                        af[mi], bf[ni], acc[mi][ni], 0, 0, 0);
        }
    }

    // epilogue: C/D layout col = lane&15, row = quad*4 + reg
    float tmax = 0.f;
#pragma unroll
    for (int ni = 0; ni < 4; ++ni) {
        int col = n0 + wn + ni * 16 + l16;
        float s = fc_sf[col];
        float bbv = bb[col];
#pragma unroll
        for (int mi = 0; mi < 4; ++mi) {
            int rowb = m0 + wm + mi * 16 + quad * 4;
#pragma unroll
            for (int r = 0; r < 4; ++r) {
                float vv = acc[mi][ni][r] * s + bbv;
                vv = fmaxf(vv, 0.f);           // ReLU
                tmax = fmaxf(tmax, vv);
                C[(size_t)(rowb + r) * OUT_DIM + col] = vv;
            }
        }
    }
#pragma unroll
    for (int off = 32; off > 0; off >>= 1)
        tmax = fmaxf(tmax, __shfl_down(tmax, off, 64));
    if (lane == 0) redm[w] = tmax;
    __syncthreads();
    if (t == 0) {
        float bmax = fmaxf(fmaxf(redm[0], redm[1]), fmaxf(redm[2], redm[3]));
        atomicMax((int*)gmax, __float_as_int(bmax));   // values >= 0
    }
}

// ---- Kernel 3: per-tensor requant, in place, 16 elems/thread ---------------
// x_min = 0 exactly (post-ReLU) -> zp = 0.
__global__ __launch_bounds__(256) void requant(float* __restrict__ C,
    const float* __restrict__ gmax, float* __restrict__ sf_out)
{
    float sf = fmaxf(gmax[0], 1e-8f) / 255.0f;
    size_t i = ((size_t)blockIdx.x * 256 + threadIdx.x) * 16;
#pragma unroll
    for (int j = 0; j < 4; ++j) {
        float4 v = *(const float4*)(C + i + j * 4);
        v.x = fminf(rintf(v.x / sf), 255.f) * sf;
        v.y = fminf(rintf(v.y / sf), 255.f) * sf;
        v.z = fminf(rintf(v.z / sf), 255.f) * sf;
        v.w = fminf(rintf(v.w / sf), 255.f) * sf;
        *(float4*)(C + i + j * 4) = v;
    }
    if (i == 0) sf_out[0] = sf;
}

extern "C" void kernel_launch(void* const* d_in, const int* in_sizes, int n_in,
                              void* d_out, int out_size, void* d_ws, size_t ws_size,
                              hipStream_t stream)
{
    const float* x      = (const float*)d_in[0];
    const float* act_sf = (const float*)d_in[1];
    const float* W      = (const float*)d_in[2];
    const float* b      = (const float*)d_in[3];

    float* out        = (float*)d_out;                       // [8192*4096] x_out
    float* fc_sf_out  = out + (size_t)B_DIM * OUT_DIM;       // [4096]
    float* act_sf_out = fc_sf_out + OUT_DIM;                 // [1]

    char* ws = (char*)d_ws;
    float* bb   = (float*)ws;                                // 4096 floats
    float* gmax = (float*)(ws + 16384);                      // 1 float
    unsigned short* xq = (unsigned short*)(ws + 32768);      // x bf16
    unsigned short* wq = xq + (size_t)B_DIM * IN_DIM;        // w_int bf16

    prep<<<OUT_DIM + (B_DIM * IN_DIM) / 2048, 256, 0, stream>>>(
        W, b, act_sf, x, wq, xq, fc_sf_out, bb, gmax);
    gemm_bt<<<(B_DIM / 128) * (OUT_DIM / 128), 256, 0, stream>>>(
        xq, wq, fc_sf_out, bb, out, gmax);
    requant<<<(B_DIM * OUT_DIM) / 4096, 256, 0, stream>>>(out, gmax, act_sf_out);
}

// Round 4
// 619.821 us; speedup vs baseline: 1.0323x; 1.0200x over previous
//
#include <hip/hip_runtime.h>
#include <hip/hip_bf16.h>
#include <stdint.h>

#define B_DIM 8192
#define IN_DIM 4096
#define OUT_DIM 4096

typedef __attribute__((ext_vector_type(8))) short s16x8;
typedef __attribute__((ext_vector_type(4))) float f32x4;

__device__ __forceinline__ unsigned short f2bf_rn(float f) {
    unsigned int u = __float_as_uint(f);
    u = (u + 0x7FFFu + ((u >> 16) & 1u)) >> 16;
    return (unsigned short)u;
}

__device__ __forceinline__ void async16(unsigned short* l, const unsigned short* g) {
    __builtin_amdgcn_global_load_lds(
        (const __attribute__((address_space(1))) void*)g,
        (__attribute__((address_space(3))) void*)l, 16, 0, 0);
}

// ---- Kernel 1: fused weight-quant (blocks 0..4095) + x->bf16 (rest) --------
__global__ __launch_bounds__(256) void prep(
    const float* __restrict__ W, const float* __restrict__ b,
    const float* __restrict__ act_sf, const float* __restrict__ x,
    unsigned short* __restrict__ wq, unsigned short* __restrict__ xq,
    float* __restrict__ fc_sf_out, float* __restrict__ bb,
    float* __restrict__ gmax)
{
    __shared__ float red[4];
    int t = threadIdx.x;
    if (blockIdx.x < OUT_DIM) {
        int o = blockIdx.x;
        const float4* Wr = (const float4*)(W + (size_t)o * IN_DIM);
        float4 v[4];
        float amax = 0.f;
#pragma unroll
        for (int j = 0; j < 4; ++j) {
            v[j] = Wr[t + j * 256];
            amax = fmaxf(amax, fmaxf(fmaxf(fabsf(v[j].x), fabsf(v[j].y)),
                                     fmaxf(fabsf(v[j].z), fabsf(v[j].w))));
        }
#pragma unroll
        for (int off = 32; off > 0; off >>= 1)
            amax = fmaxf(amax, __shfl_down(amax, off, 64));
        if ((t & 63) == 0) red[t >> 6] = amax;
        __syncthreads();
        float wmax = fmaxf(fmaxf(red[0], red[1]), fmaxf(red[2], red[3]));
        float sf = fmaxf(wmax, 1e-8f) / 127.0f;   // fc_sf

        unsigned short* wr = wq + (size_t)o * IN_DIM;
#pragma unroll
        for (int j = 0; j < 4; ++j) {
            ushort4 q;
            q.x = f2bf_rn(fminf(fmaxf(rintf(v[j].x / sf), -128.f), 127.f));
            q.y = f2bf_rn(fminf(fmaxf(rintf(v[j].y / sf), -128.f), 127.f));
            q.z = f2bf_rn(fminf(fmaxf(rintf(v[j].z / sf), -128.f), 127.f));
            q.w = f2bf_rn(fminf(fmaxf(rintf(v[j].w / sf), -128.f), 127.f));
            ((ushort4*)wr)[t + j * 256] = q;
        }
        if (t == 0) {
            fc_sf_out[o] = sf;
            float bsf = sf * act_sf[0];          // bias_sf
            float bi = rintf(b[o] / bsf);        // b_int
            bb[o] = bi * bsf;                    // folded bias
            if (o == 0) gmax[0] = 0.f;           // ws is poisoned each launch
        }
    } else {
        size_t i = ((size_t)(blockIdx.x - OUT_DIM) * 256 + t) * 8;
#pragma unroll
        for (int j = 0; j < 2; ++j) {
            float4 v = *(const float4*)(x + i + j * 4);
            ushort4 q;
            q.x = f2bf_rn(v.x); q.y = f2bf_rn(v.y);
            q.z = f2bf_rn(v.z); q.w = f2bf_rn(v.w);
            *(ushort4*)(xq + i + j * 4) = q;
        }
    }
}

// ---- Kernel 2: GEMM C = A * B^T, fused scale+bias+ReLU+global-max ----------
// 128x128 tile, BK=64, XOR-swizzled LDS (conflict-free, verified R3: 0).
// NEW: epilogue transposes acc through LDS (reusing sA/sB as a 64x130 fp32
// stage, 2 phases) so C stores are full-cache-line contiguous — kills the
// write-allocate RMW fetch (~134 MB) seen in R3's FETCH_SIZE. CB16: C stored
// as bf16 (halves WRITE and requant FETCH; adds <=1 requant level of error).
template <bool CB16>
__global__ __launch_bounds__(256) void gemm_bt(
    const unsigned short* __restrict__ A, const unsigned short* __restrict__ Bw,
    const float* __restrict__ fc_sf, const float* __restrict__ bb,
    void* __restrict__ Cout, float* __restrict__ gmax)
{
    __shared__ __align__(16) unsigned char smem[33296];
    unsigned short* sA = (unsigned short*)smem;            // 16 KB (K-loop)
    unsigned short* sB = (unsigned short*)(smem + 16384);  // 16 KB (K-loop)
    float* stage = (float*)smem;                           // 64x130 fp32 (epilogue)
    float* redm  = (float*)(smem + 33280);                 // 4 floats

    int t = threadIdx.x;
    int bn = blockIdx.x & 31;      // N/128 = 32
    int bm = blockIdx.x >> 5;      // M/128 = 64
    int lane = t & 63;
    int w = t >> 6;
    int quad = lane >> 4;
    int l16 = lane & 15;
    int m0 = bm * 128, n0 = bn * 128;
    int wm = (w & 1) * 64, wn = (w >> 1) * 64;

    // staging: slot s = j*256 + t, row r = j*32 + (t>>3), chunk gc = (t&7)^(r&7)
    int r0 = t >> 3;
    int gc = (t & 7) ^ (r0 & 7);
    const unsigned short* gA[4];
    const unsigned short* gB[4];
    unsigned short* lA[4];
    unsigned short* lB[4];
#pragma unroll
    for (int j = 0; j < 4; ++j) {
        gA[j] = A + (size_t)(m0 + j * 32 + r0) * IN_DIM + gc * 8;
        gB[j] = Bw + (size_t)(n0 + j * 32 + r0) * IN_DIM + gc * 8;
        lA[j] = sA + (j * 256 + t) * 8;
        lB[j] = sB + (j * 256 + t) * 8;
    }

    // fragment reads: half h, k-quad q -> chunk-slot (4h+q) ^ (l16&7)
    int swzl = l16 & 7;
    const unsigned short* pa[2];
    const unsigned short* pb[2];
#pragma unroll
    for (int h = 0; h < 2; ++h) {
        pa[h] = sA + (wm + l16) * 64 + ((4 * h + quad) ^ swzl) * 8;
        pb[h] = sB + (wn + l16) * 64 + ((4 * h + quad) ^ swzl) * 8;
    }

    f32x4 acc[4][4];
#pragma unroll
    for (int mi = 0; mi < 4; ++mi)
#pragma unroll
        for (int ni = 0; ni < 4; ++ni)
            acc[mi][ni] = (f32x4){0.f, 0.f, 0.f, 0.f};

    for (int kk = 0; kk < IN_DIM; kk += 64) {
        __syncthreads();
#pragma unroll
        for (int j = 0; j < 4; ++j) {
            async16(lA[j], gA[j] + kk);
            async16(lB[j], gB[j] + kk);
        }
        asm volatile("s_waitcnt vmcnt(0)" ::: "memory");
        __syncthreads();

#pragma unroll
        for (int h = 0; h < 2; ++h) {
            s16x8 af[4], bf[4];
#pragma unroll
            for (int i = 0; i < 4; ++i) af[i] = *(const s16x8*)(pa[h] + i * 16 * 64);
#pragma unroll
            for (int i = 0; i < 4; ++i) bf[i] = *(const s16x8*)(pb[h] + i * 16 * 64);
#pragma unroll
            for (int mi = 0; mi < 4; ++mi)
#pragma unroll
                for (int ni = 0; ni < 4; ++ni)
                    acc[mi][ni] = __builtin_amdgcn_mfma_f32_16x16x32_bf16(
                        af[mi], bf[ni], acc[mi][ni], 0, 0, 0);
        }
    }

    // ---- epilogue: scale+bias+ReLU into acc, track max -----------------
    float sc[4], bv[4];
#pragma unroll
    for (int ni = 0; ni < 4; ++ni) {
        int col = n0 + wn + ni * 16 + l16;
        sc[ni] = fc_sf[col];
        bv[ni] = bb[col];
    }
    float tmax = 0.f;
#pragma unroll
    for (int mi = 0; mi < 4; ++mi)
#pragma unroll
        for (int ni = 0; ni < 4; ++ni)
#pragma unroll
            for (int r = 0; r < 4; ++r) {
                float vv = fmaxf(acc[mi][ni][r] * sc[ni] + bv[ni], 0.f);
                acc[mi][ni][r] = vv;
                tmax = fmaxf(tmax, vv);
            }
#pragma unroll
    for (int off = 32; off > 0; off >>= 1)
        tmax = fmaxf(tmax, __shfl_down(tmax, off, 64));
    if (lane == 0) redm[w] = tmax;   // ordered before phase barriers below

    // ---- two-phase LDS transpose -> full-line C stores -----------------
#pragma unroll
    for (int p = 0; p < 2; ++p) {
        __syncthreads();             // protects sA/sB (p=0) / stage (p=1)
        if ((w & 1) == p) {
            // this wave's rows are m0 + p*64 + [0,64)
#pragma unroll
            for (int mi = 0; mi < 4; ++mi)
#pragma unroll
                for (int ni = 0; ni < 4; ++ni)
#pragma unroll
                    for (int r = 0; r < 4; ++r) {
                        int lrow = mi * 16 + quad * 4 + r;
                        stage[lrow * 130 + wn + ni * 16 + l16] = acc[mi][ni][r];
                    }
        }
        __syncthreads();
        int row = t >> 2;
        int cc = (t & 3) * 32;
        const float* src = stage + row * 130 + cc;
        size_t gbase = (size_t)(m0 + p * 64 + row) * OUT_DIM + n0 + cc;
        if (CB16) {
            unsigned short* dst = (unsigned short*)Cout + gbase;
#pragma unroll
            for (int j = 0; j < 4; ++j) {
                float4 v0 = *(const float4*)(src + j * 8);
                float4 v1 = *(const float4*)(src + j * 8 + 4);
                s16x8 q;
                q[0] = (short)f2bf_rn(v0.x); q[1] = (short)f2bf_rn(v0.y);
                q[2] = (short)f2bf_rn(v0.z); q[3] = (short)f2bf_rn(v0.w);
                q[4] = (short)f2bf_rn(v1.x); q[5] = (short)f2bf_rn(v1.y);
                q[6] = (short)f2bf_rn(v1.z); q[7] = (short)f2bf_rn(v1.w);
                *(s16x8*)(dst + j * 8) = q;
            }
        } else {
            float* dst = (float*)Cout + gbase;
#pragma unroll
            for (int j = 0; j < 8; ++j)
                *(float4*)(dst + j * 4) = *(const float4*)(src + j * 4);
        }
    }
    if (t == 0) {
        float bmax = fmaxf(fmaxf(redm[0], redm[1]), fmaxf(redm[2], redm[3]));
        atomicMax((int*)gmax, __float_as_int(bmax));   // values >= 0
    }
}

// ---- Kernel 3: per-tensor requant, 16 elems/thread -------------------------
// x_min = 0 exactly (post-ReLU) -> zp = 0.
template <bool CB16>
__global__ __launch_bounds__(256) void requant(const void* __restrict__ Cin,
    float* __restrict__ out, const float* __restrict__ gmax,
    float* __restrict__ sf_out)
{
    float sf = fmaxf(gmax[0], 1e-8f) / 255.0f;
    size_t i = ((size_t)blockIdx.x * 256 + threadIdx.x) * 16;
    if (CB16) {
        const unsigned short* cq = (const unsigned short*)Cin + i;
#pragma unroll
        for (int j = 0; j < 4; ++j) {
            ushort4 q = *(const ushort4*)(cq + j * 4);
            float4 v;
            v.x = __uint_as_float((unsigned)q.x << 16);
            v.y = __uint_as_float((unsigned)q.y << 16);
            v.z = __uint_as_float((unsigned)q.z << 16);
            v.w = __uint_as_float((unsigned)q.w << 16);
            v.x = fminf(rintf(v.x / sf), 255.f) * sf;
            v.y = fminf(rintf(v.y / sf), 255.f) * sf;
            v.z = fminf(rintf(v.z / sf), 255.f) * sf;
            v.w = fminf(rintf(v.w / sf), 255.f) * sf;
            *(float4*)(out + i + j * 4) = v;
        }
    } else {
        float* C = out;   // in place
#pragma unroll
        for (int j = 0; j < 4; ++j) {
            float4 v = *(const float4*)(C + i + j * 4);
            v.x = fminf(rintf(v.x / sf), 255.f) * sf;
            v.y = fminf(rintf(v.y / sf), 255.f) * sf;
            v.z = fminf(rintf(v.z / sf), 255.f) * sf;
            v.w = fminf(rintf(v.w / sf), 255.f) * sf;
            *(float4*)(C + i + j * 4) = v;
        }
    }
    if (i == 0) sf_out[0] = sf;
}

extern "C" void kernel_launch(void* const* d_in, const int* in_sizes, int n_in,
                              void* d_out, int out_size, void* d_ws, size_t ws_size,
                              hipStream_t stream)
{
    const float* x      = (const float*)d_in[0];
    const float* act_sf = (const float*)d_in[1];
    const float* W      = (const float*)d_in[2];
    const float* b      = (const float*)d_in[3];

    float* out        = (float*)d_out;                       // [8192*4096] x_out
    float* fc_sf_out  = out + (size_t)B_DIM * OUT_DIM;       // [4096]
    float* act_sf_out = fc_sf_out + OUT_DIM;                 // [1]

    char* ws = (char*)d_ws;
    float* bb   = (float*)ws;                                // 4096 floats
    float* gmax = (float*)(ws + 16384);                      // 1 float
    unsigned short* xq = (unsigned short*)(ws + 32768);      // x bf16 (64 MiB)
    unsigned short* wq = xq + (size_t)B_DIM * IN_DIM;        // w_int bf16 (32 MiB)
    unsigned short* cq = wq + (size_t)OUT_DIM * IN_DIM;      // C bf16 (64 MiB)

    size_t need = 32768 + ((size_t)B_DIM * IN_DIM + (size_t)OUT_DIM * IN_DIM
                           + (size_t)B_DIM * OUT_DIM) * 2;

    prep<<<OUT_DIM + (B_DIM * IN_DIM) / 2048, 256, 0, stream>>>(
        W, b, act_sf, x, wq, xq, fc_sf_out, bb, gmax);

    int gemm_grid = (B_DIM / 128) * (OUT_DIM / 128);
    int rq_grid = (B_DIM * OUT_DIM) / 4096;
    if (ws_size >= need) {
        gemm_bt<true><<<gemm_grid, 256, 0, stream>>>(
            xq, wq, fc_sf_out, bb, (void*)cq, gmax);
        requant<true><<<rq_grid, 256, 0, stream>>>(
            (const void*)cq, out, gmax, act_sf_out);
    } else {
        gemm_bt<false><<<gemm_grid, 256, 0, stream>>>(
            xq, wq, fc_sf_out, bb, (void*)out, gmax);
        requant<false><<<rq_grid, 256, 0, stream>>>(
            (const void*)out, out, gmax, act_sf_out);
    }
}